// Round 3
// baseline (1473.942 us; speedup 1.0000x reference)
//
#include <hip/hip_runtime.h>
#include <cstdint>
#include <cstddef>

#define LN_EPS 1e-5f
#define STR 136   // padded LDS row stride in bf16 elems (136*2=272B, 16B-mult)
#define WSTR 128  // dense global weight stride (bf16 elems)

typedef unsigned short u16;
typedef unsigned int   u32;
typedef __attribute__((ext_vector_type(8))) short bf16x8;
typedef __attribute__((ext_vector_type(4))) float f32x4;

__device__ __forceinline__ u16 f2bf(float f) {
    u32 x = __float_as_uint(f);
    return (u16)((x + 0x7fffu + ((x >> 16) & 1u)) >> 16);   // RNE, finite inputs
}

// 32 fp32 -> 32 bf16 into LDS (16B-aligned)
__device__ __forceinline__ void stage_row(const float* __restrict__ src, u16* dst) {
    const float4* s4 = reinterpret_cast<const float4*>(src);
    uint4* d4 = reinterpret_cast<uint4*>(dst);
#pragma unroll
    for (int q = 0; q < 4; q++) {
        float4 a = s4[2 * q], b = s4[2 * q + 1];
        uint4 o;
        o.x = f2bf(a.x) | ((u32)f2bf(a.y) << 16);
        o.y = f2bf(a.z) | ((u32)f2bf(a.w) << 16);
        o.z = f2bf(b.x) | ((u32)f2bf(b.y) << 16);
        o.w = f2bf(b.z) | ((u32)f2bf(b.w) << 16);
        d4[q] = o;
    }
}

// 16 fp32 (registers) -> 16 bf16 into LDS (16B-aligned)
__device__ __forceinline__ void pack16(u16* dst, const float* a) {
    uint4 o0, o1;
    o0.x = (u32)f2bf(a[0])  | ((u32)f2bf(a[1])  << 16);
    o0.y = (u32)f2bf(a[2])  | ((u32)f2bf(a[3])  << 16);
    o0.z = (u32)f2bf(a[4])  | ((u32)f2bf(a[5])  << 16);
    o0.w = (u32)f2bf(a[6])  | ((u32)f2bf(a[7])  << 16);
    o1.x = (u32)f2bf(a[8])  | ((u32)f2bf(a[9])  << 16);
    o1.y = (u32)f2bf(a[10]) | ((u32)f2bf(a[11]) << 16);
    o1.z = (u32)f2bf(a[12]) | ((u32)f2bf(a[13]) << 16);
    o1.w = (u32)f2bf(a[14]) | ((u32)f2bf(a[15]) << 16);
    reinterpret_cast<uint4*>(dst)[0] = o0;
    reinterpret_cast<uint4*>(dst)[1] = o1;
}

// ---------------------------------------------------------------------------
// prep: W1 [128,128] -> W1T bf16 [n][k] dense stride 128; W2 [128,32] -> W2T
// ---------------------------------------------------------------------------
__global__ void prep_kernel(const float* __restrict__ eW1, const float* __restrict__ eW2,
                            const float* __restrict__ nW1, const float* __restrict__ nW2,
                            u16* eW1T, u16* eW2T, u16* nW1T, u16* nW2T)
{
    int idx = blockIdx.x * 256 + threadIdx.x;
    if (idx < 16384) {
        int k = idx >> 7, n = idx & 127;
        eW1T[n * WSTR + k] = f2bf(eW1[idx]);
        nW1T[n * WSTR + k] = f2bf(nW1[idx]);
    }
    if (idx < 4096) {
        int k = idx >> 5, n = idx & 31;
        eW2T[n * WSTR + k] = f2bf(eW2[idx]);
        nW2T[n * WSTR + k] = f2bf(nW2[idx]);
    }
}

// ---------------------------------------------------------------------------
// CSR build: histogram -> exclusive scan -> fill.
// 3.2M int atomics each for hist/fill (vs 51.2M f16 RMW the scatter used).
// ---------------------------------------------------------------------------
__global__ void hist_kernel(const int* __restrict__ edge_index,
                            int* __restrict__ curS, int* __restrict__ curR, int E)
{
    int stride = gridDim.x * blockDim.x;
    for (int e = blockIdx.x * blockDim.x + threadIdx.x; e < E; e += stride) {
        atomicAdd(&curS[edge_index[e]], 1);            // row = send side
        atomicAdd(&curR[edge_index[(long)E + e]], 1);  // col = recv side
    }
}

// single-block exclusive scan of curS/curR (N ints each); writes offX (segment
// starts, kept for readers) and rewrites curX = offX (fill cursors).
__global__ void scan_kernel(int* __restrict__ curS, int* __restrict__ curR,
                            int* __restrict__ offS, int* __restrict__ offR, int N)
{
    __shared__ int tmp[1024];
    const int t = threadIdx.x;
#pragma unroll 1
    for (int pass = 0; pass < 2; pass++) {
        int* cur = pass ? curR : curS;
        int* off = pass ? offR : offS;
        int carry = 0;
#pragma unroll 1
        for (int base = 0; base < N; base += 1024) {
            int i = base + t;
            int v = (i < N) ? cur[i] : 0;
            tmp[t] = v;
            __syncthreads();
#pragma unroll 1
            for (int d = 1; d < 1024; d <<= 1) {
                int x = (t >= d) ? tmp[t - d] : 0;
                __syncthreads();
                tmp[t] += x;
                __syncthreads();
            }
            int excl = carry + tmp[t] - v;
            if (i < N) { off[i] = excl; cur[i] = excl; }
            carry += tmp[1023];
            __syncthreads();
        }
    }
}

__global__ void fill_kernel(const int* __restrict__ edge_index,
                            int* __restrict__ curS, int* __restrict__ curR,
                            int* __restrict__ lstS, int* __restrict__ lstR, int E)
{
    int stride = gridDim.x * blockDim.x;
    for (int e = blockIdx.x * blockDim.x + threadIdx.x; e < E; e += stride) {
        int row = edge_index[e];
        int col = edge_index[(long)E + e];
        int p = atomicAdd(&curS[row], 1); lstS[p] = e;
        int q = atomicAdd(&curR[col], 1); lstR[q] = e;
    }
    // post: curS[n] == end of node n's send list (= offS[n] + degS[n])
}

// ---------------------------------------------------------------------------
// Edge model, MFMA. Each wave independently handles 32 edges.
// NO scatter atomics (the R2 bottleneck: 51.2M device-scope f16 RMW ~= the
// whole kernel duration; occupancy-doubling did nothing because the atomic
// pipe is a shared serialized resource). Aggregation is now gather-side.
// ---------------------------------------------------------------------------
__global__ __launch_bounds__(256, 4)
void edge_mfma(const float* __restrict__ edge_attr,
               const float* __restrict__ node_attr,
               const float* __restrict__ global_attr,
               const int* __restrict__ edge_index,
               const int* __restrict__ batch,
               const u16* __restrict__ W1T, const float* __restrict__ b1,
               const u16* __restrict__ W2T, const float* __restrict__ b2,
               const float* __restrict__ gamma, const float* __restrict__ beta,
               float* __restrict__ edge_out,
               int E)
{
    __shared__ __align__(16) u16 sEin[4][32 * STR];

    const int tid = threadIdx.x;
    const int wave = tid >> 6;
    const int lane = tid & 63;
    const int quad = lane >> 4;
    const int ln   = lane & 15;
    u16* Ein = sEin[wave];

    const long e0 = ((long)blockIdx.x * 4 + wave) * 32;

    // ---- stage gathered e_in = [node[col] | node[row] | edge | global] ----
    {
        int eL  = lane >> 2;
        int seg = lane & 3;
#pragma unroll
        for (int t = 0; t < 2; t++, eL += 16) {
            long e = e0 + eL;
            long ec = e < E ? e : (long)E - 1;
            int row = edge_index[ec];
            int col = edge_index[(long)E + ec];
            const float* src;
            if (seg == 0)      { src = node_attr + (long)col * 32; }
            else if (seg == 1) { src = node_attr + (long)row * 32; }
            else if (seg == 2) { src = edge_attr + ec * 32; }
            else               { src = global_attr + (long)batch[row] * 32; }
            stage_row(src, Ein + eL * STR + seg * 32);
        }
    }

    // ---- GEMM1: H = relu(Ein @ W1 + b1) ----
    f32x4 acc1[2][8];
#pragma unroll
    for (int mt = 0; mt < 2; mt++)
#pragma unroll
        for (int nt = 0; nt < 8; nt++) acc1[mt][nt] = (f32x4)0.f;

#pragma unroll
    for (int ks = 0; ks < 4; ks++) {
        const int ko = ks * 32 + quad * 8;
        bf16x8 a0 = *reinterpret_cast<const bf16x8*>(Ein + (ln) * STR + ko);
        bf16x8 a1 = *reinterpret_cast<const bf16x8*>(Ein + (16 + ln) * STR + ko);
#pragma unroll
        for (int nt = 0; nt < 8; nt++) {
            bf16x8 bf = *reinterpret_cast<const bf16x8*>(W1T + (nt * 16 + ln) * WSTR + ko);
            acc1[0][nt] = __builtin_amdgcn_mfma_f32_16x16x32_bf16(a0, bf, acc1[0][nt], 0, 0, 0);
            acc1[1][nt] = __builtin_amdgcn_mfma_f32_16x16x32_bf16(a1, bf, acc1[1][nt], 0, 0, 0);
        }
    }

    // ---- bias+relu, H -> LDS (A-operand layout) ----
#pragma unroll
    for (int nt = 0; nt < 8; nt++) {
        float bias = b1[nt * 16 + ln];
#pragma unroll
        for (int mt = 0; mt < 2; mt++)
#pragma unroll
            for (int r = 0; r < 4; r++) {
                float h = fmaxf(acc1[mt][nt][r] + bias, 0.f);
                int rowl = mt * 16 + quad * 4 + r;
                Ein[rowl * STR + nt * 16 + ln] = f2bf(h);
            }
    }

    // ---- GEMM2 ----
    f32x4 acc2[2][2];
#pragma unroll
    for (int mt = 0; mt < 2; mt++)
#pragma unroll
        for (int nt = 0; nt < 2; nt++) acc2[mt][nt] = (f32x4)0.f;

#pragma unroll
    for (int ks = 0; ks < 4; ks++) {
        const int ko = ks * 32 + quad * 8;
        bf16x8 a0 = *reinterpret_cast<const bf16x8*>(Ein + (ln) * STR + ko);
        bf16x8 a1 = *reinterpret_cast<const bf16x8*>(Ein + (16 + ln) * STR + ko);
#pragma unroll
        for (int nt = 0; nt < 2; nt++) {
            bf16x8 bf = *reinterpret_cast<const bf16x8*>(W2T + (nt * 16 + ln) * WSTR + ko);
            acc2[0][nt] = __builtin_amdgcn_mfma_f32_16x16x32_bf16(a0, bf, acc2[0][nt], 0, 0, 0);
            acc2[1][nt] = __builtin_amdgcn_mfma_f32_16x16x32_bf16(a1, bf, acc2[1][nt], 0, 0, 0);
        }
    }

    // ---- epilogue: relu, LN, store (plain stores: node kernel re-reads) ----
    float g0 = gamma[ln],    g1 = gamma[16 + ln];
    float B0 = beta[ln],     B1 = beta[16 + ln];
    float bb0 = b2[ln],      bb1 = b2[16 + ln];

#pragma unroll
    for (int mt = 0; mt < 2; mt++) {
#pragma unroll
        for (int r = 0; r < 4; r++) {
            float v0 = fmaxf(acc2[mt][0][r] + bb0, 0.f);
            float v1 = fmaxf(acc2[mt][1][r] + bb1, 0.f);
            float s = v0 + v1, sq = v0 * v0 + v1 * v1;
#pragma unroll
            for (int m = 1; m < 16; m <<= 1) {
                s  += __shfl_xor(s,  m, 64);
                sq += __shfl_xor(sq, m, 64);
            }
            float mean = s * (1.f / 32.f);
            float var  = fmaxf(sq * (1.f / 32.f) - mean * mean, 0.f);
            float rs   = rsqrtf(var + LN_EPS);
            float y0 = (v0 - mean) * rs * g0 + B0;
            float y1 = (v1 - mean) * rs * g1 + B1;
            int rowl = mt * 16 + quad * 4 + r;
            long e = e0 + rowl;
            if (e < E) {
                edge_out[e * 32 + ln]      = y0;
                edge_out[e * 32 + 16 + ln] = y1;
            }
        }
    }
}

// ---------------------------------------------------------------------------
// Node model, MFMA. send/recv aggregates computed by GATHER over CSR lists
// (fp32 accumulate in registers; 2 lanes per node, 16 feats each).
// n2g/e2g via block-level LDS reduction as before.
// ---------------------------------------------------------------------------
__global__ __launch_bounds__(128, 4)
void node_mfma(const float* __restrict__ node_attr,
               const float* __restrict__ global_attr,
               const int* __restrict__ batch,
               const float* __restrict__ edge_out,
               const int* __restrict__ offS, const int* __restrict__ curS,
               const int* __restrict__ offR, const int* __restrict__ curR,
               const int* __restrict__ lstS, const int* __restrict__ lstR,
               const u16* __restrict__ W1T, const float* __restrict__ b1,
               const u16* __restrict__ W2T, const float* __restrict__ b2,
               const float* __restrict__ gamma, const float* __restrict__ beta,
               float* __restrict__ node_out,
               float* __restrict__ n2g, float* __restrict__ e2g,
               int N)
{
    __shared__ __align__(16) u16 sEin[2][32 * STR];
    __shared__ int sGb[2][32];
    __shared__ float sRed[8][64];       // [slot][n2g 0..31 | e2g 32..63]
    __shared__ int sSlotGb[8];
    __shared__ int sGbFirst;

    const int tid = threadIdx.x;
    {
        for (int i = tid; i < 512; i += 128) ((float*)sRed)[i] = 0.f;
        if (tid < 8) sSlotGb[tid] = -1;
        if (tid == 0) {
            long nb = (long)blockIdx.x * 64;
            sGbFirst = batch[nb < N ? nb : N - 1];
        }
    }
    __syncthreads();

    const int wave = tid >> 6;
    const int lane = tid & 63;
    const int quad = lane >> 4;
    const int ln   = lane & 15;
    u16* Ein = sEin[wave];
    int* gbb = sGb[wave];
    const int gbF = sGbFirst;

    const long n0 = ((long)blockIdx.x * 2 + wave) * 32;

    // ---- stage node_attr (cols 0..31) + global (cols 32..63) ----
    {
        int eL  = lane >> 1;
        int seg = lane & 1;
        long n = n0 + eL;
        long nc = n < N ? n : (long)N - 1;
        u16* dst = Ein + eL * STR + seg * 32;
        if (seg == 0) { stage_row(node_attr + nc * 32, dst); }
        else          { int gb = batch[nc]; gbb[eL] = gb;
                        stage_row(global_attr + (long)gb * 32, dst); }
    }

    // ---- gather send/recv aggregates from edge_out via CSR ----
    {
        const int nodeRow = lane >> 1;
        const int half = lane & 1;
        const long n = n0 + nodeRow;
        const bool valid = n < N;
        float acc[16];

        // --- send: edges with row == n ---
#pragma unroll
        for (int i = 0; i < 16; i++) acc[i] = 0.f;
        if (valid) {
            int j = offS[n], jend = curS[n];
            for (; j + 1 < jend; j += 2) {
                int ea = lstS[j], eb = lstS[j + 1];
                const float4* pa = reinterpret_cast<const float4*>(edge_out + (long)ea * 32 + half * 16);
                const float4* pb = reinterpret_cast<const float4*>(edge_out + (long)eb * 32 + half * 16);
#pragma unroll
                for (int q = 0; q < 4; q++) {
                    float4 va = pa[q], vb = pb[q];
                    acc[q * 4 + 0] += va.x + vb.x;
                    acc[q * 4 + 1] += va.y + vb.y;
                    acc[q * 4 + 2] += va.z + vb.z;
                    acc[q * 4 + 3] += va.w + vb.w;
                }
            }
            if (j < jend) {
                int ea = lstS[j];
                const float4* pa = reinterpret_cast<const float4*>(edge_out + (long)ea * 32 + half * 16);
#pragma unroll
                for (int q = 0; q < 4; q++) {
                    float4 va = pa[q];
                    acc[q * 4 + 0] += va.x;
                    acc[q * 4 + 1] += va.y;
                    acc[q * 4 + 2] += va.z;
                    acc[q * 4 + 3] += va.w;
                }
            }
        }
        pack16(Ein + nodeRow * STR + 96 + half * 16, acc);   // send_agg cols 96..127
        if (valid) {   // e2g = per-graph sum of send aggregates
            int gb = gbb[nodeRow];
            int slot = gb - gbF;
            if (slot >= 0 && slot < 8) {
#pragma unroll
                for (int i = 0; i < 16; i++)
                    atomicAdd(&sRed[slot][32 + half * 16 + i], acc[i]);
            } else {
#pragma unroll
                for (int i = 0; i < 16; i++)
                    unsafeAtomicAdd(e2g + (long)gb * 32 + half * 16 + i, acc[i]);
            }
        }

        // --- recv: edges with col == n ---
#pragma unroll
        for (int i = 0; i < 16; i++) acc[i] = 0.f;
        if (valid) {
            int j = offR[n], jend = curR[n];
            for (; j + 1 < jend; j += 2) {
                int ea = lstR[j], eb = lstR[j + 1];
                const float4* pa = reinterpret_cast<const float4*>(edge_out + (long)ea * 32 + half * 16);
                const float4* pb = reinterpret_cast<const float4*>(edge_out + (long)eb * 32 + half * 16);
#pragma unroll
                for (int q = 0; q < 4; q++) {
                    float4 va = pa[q], vb = pb[q];
                    acc[q * 4 + 0] += va.x + vb.x;
                    acc[q * 4 + 1] += va.y + vb.y;
                    acc[q * 4 + 2] += va.z + vb.z;
                    acc[q * 4 + 3] += va.w + vb.w;
                }
            }
            if (j < jend) {
                int ea = lstR[j];
                const float4* pa = reinterpret_cast<const float4*>(edge_out + (long)ea * 32 + half * 16);
#pragma unroll
                for (int q = 0; q < 4; q++) {
                    float4 va = pa[q];
                    acc[q * 4 + 0] += va.x;
                    acc[q * 4 + 1] += va.y;
                    acc[q * 4 + 2] += va.z;
                    acc[q * 4 + 3] += va.w;
                }
            }
        }
        pack16(Ein + nodeRow * STR + 64 + half * 16, acc);   // recv_agg cols 64..95
    }

    // ---- GEMM1 ----
    f32x4 acc1[2][8];
#pragma unroll
    for (int mt = 0; mt < 2; mt++)
#pragma unroll
        for (int nt = 0; nt < 8; nt++) acc1[mt][nt] = (f32x4)0.f;

#pragma unroll
    for (int ks = 0; ks < 4; ks++) {
        const int ko = ks * 32 + quad * 8;
        bf16x8 a0 = *reinterpret_cast<const bf16x8*>(Ein + (ln) * STR + ko);
        bf16x8 a1 = *reinterpret_cast<const bf16x8*>(Ein + (16 + ln) * STR + ko);
#pragma unroll
        for (int nt = 0; nt < 8; nt++) {
            bf16x8 bf = *reinterpret_cast<const bf16x8*>(W1T + (nt * 16 + ln) * WSTR + ko);
            acc1[0][nt] = __builtin_amdgcn_mfma_f32_16x16x32_bf16(a0, bf, acc1[0][nt], 0, 0, 0);
            acc1[1][nt] = __builtin_amdgcn_mfma_f32_16x16x32_bf16(a1, bf, acc1[1][nt], 0, 0, 0);
        }
    }

#pragma unroll
    for (int nt = 0; nt < 8; nt++) {
        float bias = b1[nt * 16 + ln];
#pragma unroll
        for (int mt = 0; mt < 2; mt++)
#pragma unroll
            for (int r = 0; r < 4; r++) {
                float h = fmaxf(acc1[mt][nt][r] + bias, 0.f);
                int rowl = mt * 16 + quad * 4 + r;
                Ein[rowl * STR + nt * 16 + ln] = f2bf(h);
            }
    }

    // ---- GEMM2 ----
    f32x4 acc2[2][2];
#pragma unroll
    for (int mt = 0; mt < 2; mt++)
#pragma unroll
        for (int nt = 0; nt < 2; nt++) acc2[mt][nt] = (f32x4)0.f;

#pragma unroll
    for (int ks = 0; ks < 4; ks++) {
        const int ko = ks * 32 + quad * 8;
        bf16x8 a0 = *reinterpret_cast<const bf16x8*>(Ein + (ln) * STR + ko);
        bf16x8 a1 = *reinterpret_cast<const bf16x8*>(Ein + (16 + ln) * STR + ko);
#pragma unroll
        for (int nt = 0; nt < 2; nt++) {
            bf16x8 bf = *reinterpret_cast<const bf16x8*>(W2T + (nt * 16 + ln) * WSTR + ko);
            acc2[0][nt] = __builtin_amdgcn_mfma_f32_16x16x32_bf16(a0, bf, acc2[0][nt], 0, 0, 0);
            acc2[1][nt] = __builtin_amdgcn_mfma_f32_16x16x32_bf16(a1, bf, acc2[1][nt], 0, 0, 0);
        }
    }

    float g0 = gamma[ln],    g1 = gamma[16 + ln];
    float B0 = beta[ln],     B1 = beta[16 + ln];
    float bb0 = b2[ln],      bb1 = b2[16 + ln];

#pragma unroll
    for (int mt = 0; mt < 2; mt++) {
#pragma unroll
        for (int r = 0; r < 4; r++) {
            float v0 = fmaxf(acc2[mt][0][r] + bb0, 0.f);
            float v1 = fmaxf(acc2[mt][1][r] + bb1, 0.f);
            float s = v0 + v1, sq = v0 * v0 + v1 * v1;
#pragma unroll
            for (int m = 1; m < 16; m <<= 1) {
                s  += __shfl_xor(s,  m, 64);
                sq += __shfl_xor(sq, m, 64);
            }
            float mean = s * (1.f / 32.f);
            float var  = fmaxf(sq * (1.f / 32.f) - mean * mean, 0.f);
            float rs   = rsqrtf(var + LN_EPS);
            float y0 = (v0 - mean) * rs * g0 + B0;
            float y1 = (v1 - mean) * rs * g1 + B1;
            int rowl = mt * 16 + quad * 4 + r;
            long n = n0 + rowl;
            if (n < N) {
                node_out[n * 32 + ln]      = y0;
                node_out[n * 32 + 16 + ln] = y1;
                int gb = gbb[rowl];
                int slot = gb - gbF;
                if (slot >= 0 && slot < 8) {
                    if (ln == 0) sSlotGb[slot] = gb;
                    atomicAdd(&sRed[slot][ln],      y0);
                    atomicAdd(&sRed[slot][16 + ln], y1);
                } else {   // pathological fallback (shouldn't happen: sorted batch)
                    unsafeAtomicAdd(n2g + (long)gb * 32 + ln,      y0);
                    unsafeAtomicAdd(n2g + (long)gb * 32 + 16 + ln, y1);
                }
            }
        }
    }

    __syncthreads();
    // flush block-level partials: 128 threads cover 8 slots x 64 feats in 4 steps
    for (int s = tid >> 6; s < 8; s += 2) {
        int f = tid & 63;
        int gb2 = sSlotGb[s];
        if (gb2 >= 0) {
            float v = sRed[s][f];
            float* dst = (f < 32) ? (n2g + (long)gb2 * 32 + f)
                                  : (e2g + (long)gb2 * 32 + (f - 32));
            unsafeAtomicAdd(dst, v);
        }
    }
}

// ---------------------------------------------------------------------------
// Global model (tiny, fp32 exact)
// ---------------------------------------------------------------------------
__global__ void global_kernel(const float* __restrict__ n2g,
                              const float* __restrict__ e2g,
                              const float* __restrict__ global_attr,
                              const float* __restrict__ W1, const float* __restrict__ b1,
                              const float* __restrict__ W2, const float* __restrict__ b2,
                              float* __restrict__ out)
{
    __shared__ float gin[96];
    __shared__ float h[128];
    int g = blockIdx.x, t = threadIdx.x;
    if (t < 32) {
        gin[t]      = n2g[g * 32 + t];
        gin[32 + t] = e2g[g * 32 + t];
        gin[64 + t] = global_attr[g * 32 + t];
    }
    __syncthreads();
    float acc = b1[t];
#pragma unroll 1
    for (int k = 0; k < 96; k++) acc = fmaf(gin[k], W1[k * 128 + t], acc);
    h[t] = fmaxf(acc, 0.f);
    __syncthreads();
    if (t < 32) {
        float o = b2[t];
#pragma unroll 1
        for (int j = 0; j < 128; j++) o = fmaf(h[j], W2[j * 32 + t], o);
        out[g * 32 + t] = fmaxf(o, 0.f);
    }
}

// ---------------------------------------------------------------------------
extern "C" void kernel_launch(void* const* d_in, const int* in_sizes, int n_in,
                              void* d_out, int out_size, void* d_ws, size_t ws_size,
                              hipStream_t stream)
{
    const float* edge_attr   = (const float*)d_in[0];
    const float* node_attr   = (const float*)d_in[1];
    const float* global_attr = (const float*)d_in[2];
    const int*   edge_index  = (const int*)d_in[3];
    const int*   batch       = (const int*)d_in[4];
    const float* eW1 = (const float*)d_in[5];
    const float* eb1 = (const float*)d_in[6];
    const float* eW2 = (const float*)d_in[7];
    const float* eb2 = (const float*)d_in[8];
    const float* eg  = (const float*)d_in[9];
    const float* eB  = (const float*)d_in[10];
    const float* nW1 = (const float*)d_in[11];
    const float* nb1 = (const float*)d_in[12];
    const float* nW2 = (const float*)d_in[13];
    const float* nb2 = (const float*)d_in[14];
    const float* ng  = (const float*)d_in[15];
    const float* nB  = (const float*)d_in[16];
    const float* gW1 = (const float*)d_in[17];
    const float* gb1 = (const float*)d_in[18];
    const float* gW2 = (const float*)d_in[19];
    const float* gb2 = (const float*)d_in[20];

    const int E = in_sizes[0] / 32;
    const int N = in_sizes[1] / 32;
    const int G = in_sizes[2] / 32;

    float* out      = (float*)d_out;
    float* edge_out = out;
    float* node_out = out + (size_t)E * 32;
    float* glob_out = out + (size_t)(E + N) * 32;

    // ws layout: [n2g f32 G*32 | e2g f32 G*32 | curS N | curR N | offS N |
    //             offR N | lstS E | lstR E | bf16 weights]
    float* n2g  = (float*)d_ws;
    float* e2g  = n2g + (size_t)G * 32;
    int*   curS = (int*)(e2g + (size_t)G * 32);
    int*   curR = curS + N;
    int*   offS = curR + N;
    int*   offR = offS + N;
    int*   lstS = offR + N;
    int*   lstR = lstS + E;
    u16* eW1T = (u16*)(lstR + E);
    u16* eW2T = eW1T + 128 * WSTR;
    u16* nW1T = eW2T + 32 * WSTR;
    u16* nW2T = nW1T + 128 * WSTR;

    // zero n2g, e2g, curS, curR (contiguous)
    size_t zero_bytes = (size_t)G * 32 * 2 * sizeof(float) + (size_t)N * 2 * sizeof(int);
    hipMemsetAsync(d_ws, 0, zero_bytes, stream);

    prep_kernel<<<64, 256, 0, stream>>>(eW1, eW2, nW1, nW2, eW1T, eW2T, nW1T, nW2T);

    hist_kernel<<<2048, 256, 0, stream>>>(edge_index, curS, curR, E);
    scan_kernel<<<1, 1024, 0, stream>>>(curS, curR, offS, offR, N);
    fill_kernel<<<2048, 256, 0, stream>>>(edge_index, curS, curR, lstS, lstR, E);

    edge_mfma<<<(E + 127) / 128, 256, 0, stream>>>(
        edge_attr, node_attr, global_attr, edge_index, batch,
        eW1T, eb1, eW2T, eb2, eg, eB,
        edge_out, E);

    node_mfma<<<(N + 63) / 64, 128, 0, stream>>>(
        node_attr, global_attr, batch, edge_out,
        offS, curS, offR, curR, lstS, lstR,
        nW1T, nb1, nW2T, nb2, ng, nB,
        node_out, n2g, e2g, N);

    global_kernel<<<G, 128, 0, stream>>>(
        n2g, e2g, global_attr, gW1, gb1, gW2, gb2, glob_out);
}

// Round 4
// 654.048 us; speedup vs baseline: 2.2536x; 2.2536x over previous
//
#include <hip/hip_runtime.h>
#include <hip/hip_fp16.h>
#include <cstdint>
#include <cstddef>

#define LN_EPS 1e-5f
#define STR 136   // padded row stride in bf16 elems (272B, 2-way LDS bank alias only)

typedef unsigned short u16;
typedef unsigned int   u32;
typedef __attribute__((ext_vector_type(8))) short bf16x8;
typedef __attribute__((ext_vector_type(4))) float f32x4;

#define MFMA16 __builtin_amdgcn_mfma_f32_16x16x32_bf16

__device__ __forceinline__ u16 f2bf(float f) {
    u32 x = __float_as_uint(f);
    return (u16)((x + 0x7fffu + ((x >> 16) & 1u)) >> 16);   // RNE, finite inputs
}
__device__ __forceinline__ u32 pack2(float x, float y) {
    return (u32)f2bf(x) | ((u32)f2bf(y) << 16);
}
__device__ __forceinline__ bf16x8 cvt8(float4 a, float4 b) {
    union { bf16x8 v; u32 w[4]; } u;
    u.w[0] = pack2(a.x, a.y); u.w[1] = pack2(a.z, a.w);
    u.w[2] = pack2(b.x, b.y); u.w[3] = pack2(b.z, b.w);
    return u.v;
}
__device__ __forceinline__ u32 h2_to_bf2(u32 h) {
    __half2 hv = *reinterpret_cast<__half2*>(&h);
    float lo = __half2float(__low2half(hv));
    float hi = __half2float(__high2half(hv));
    return pack2(lo, hi);
}
__device__ __forceinline__ bf16x8 cvtf16x8(uint4 a) {
    union { bf16x8 v; u32 w[4]; } u;
    u.w[0] = h2_to_bf2(a.x); u.w[1] = h2_to_bf2(a.y);
    u.w[2] = h2_to_bf2(a.z); u.w[3] = h2_to_bf2(a.w);
    return u.v;
}

// ---------------------------------------------------------------------------
// prep: W1 [128,128] -> W1T bf16 [n][k] stride STR; W2 [128,32] -> W2T
// ---------------------------------------------------------------------------
__global__ void prep_kernel(const float* __restrict__ eW1, const float* __restrict__ eW2,
                            const float* __restrict__ nW1, const float* __restrict__ nW2,
                            u16* eW1T, u16* eW2T, u16* nW1T, u16* nW2T)
{
    int idx = blockIdx.x * 256 + threadIdx.x;
    if (idx < 16384) {
        int k = idx >> 7, n = idx & 127;
        eW1T[n * STR + k] = f2bf(eW1[idx]);
        nW1T[n * STR + k] = f2bf(nW1[idx]);
    }
    if (idx < 4096) {
        int k = idx >> 5, n = idx & 31;
        eW2T[n * STR + k] = f2bf(eW2[idx]);
        nW2T[n * STR + k] = f2bf(nW2[idx]);
    }
}

// node_attr / global_attr f32 -> bf16 tables (halves gather bytes; A-frags
// become direct 16B register loads with zero conversion VALU in the hot loop)
__global__ void cvt_nodes(const float* __restrict__ node_attr,
                          const float* __restrict__ global_attr,
                          u16* __restrict__ nodeB, u16* __restrict__ globB,
                          int n8, int g8)
{
    int stride = gridDim.x * 256;
    for (int i = blockIdx.x * 256 + threadIdx.x; i < n8 + g8; i += stride) {
        const float4* s; uint4* d; int j;
        if (i < n8) { s = (const float4*)node_attr;   d = (uint4*)nodeB; j = i; }
        else        { s = (const float4*)global_attr; d = (uint4*)globB; j = i - n8; }
        float4 a = s[2 * j], b = s[2 * j + 1];
        uint4 o;
        o.x = pack2(a.x, a.y); o.y = pack2(a.z, a.w);
        o.z = pack2(b.x, b.y); o.w = pack2(b.z, b.w);
        d[j] = o;
    }
}

// ---------------------------------------------------------------------------
// Edge model: persistent waves, 32 edges/tile, software-pipelined.
// Key structure (R3 post-mortem: per-wave latency ~69K cyc, every pipe idle):
//  - A-fragments loaded DIRECTLY into registers (bf16 sources), no input LDS
//  - W1/W2 staged in LDS once per block -> GEMM waits are lgkmcnt-only,
//    so next-tile gather loads stay in flight across the whole compute phase
//  - af/pf register ping-pong: issue tile t+1 gathers at step start; first
//    use is ~2K cycles later (GEMM1+H+GEMM2+epilogue) -> latency hidden
//  - epilogue atomics/stores are fire-and-forget (no waits on them)
// ---------------------------------------------------------------------------
__global__ __launch_bounds__(256, 2)
void edge_mfma(const float* __restrict__ edge_attr,
               const int* __restrict__ edge_index,
               const int* __restrict__ batch,
               const u16* __restrict__ nodeB,
               const u16* __restrict__ globB,
               const u16* __restrict__ W1T, const float* __restrict__ b1,
               const u16* __restrict__ W2T, const float* __restrict__ b2,
               const float* __restrict__ gamma, const float* __restrict__ beta,
               float* __restrict__ edge_out,
               __half* __restrict__ send_agg, __half* __restrict__ recv_agg,
               int E)
{
    __shared__ __align__(16) u16 sW1[128 * STR];
    __shared__ __align__(16) u16 sW2[32 * STR];
    __shared__ __align__(16) u16 sH[4][32 * STR];
    __shared__ int2 sIdx[4][2][32];

    const int tid  = threadIdx.x;
    const int wave = tid >> 6;
    const int lane = tid & 63;
    const int quad = lane >> 4;
    const int ln   = lane & 15;

    // ---- stage weights to LDS (once per block) ----
    {
        const uint4* s1 = reinterpret_cast<const uint4*>(W1T);
        uint4* d1 = reinterpret_cast<uint4*>(sW1);
        for (int i = tid; i < 128 * STR / 8; i += 256) d1[i] = s1[i];
        const uint4* s2 = reinterpret_cast<const uint4*>(W2T);
        uint4* d2 = reinterpret_cast<uint4*>(sW2);
        for (int i = tid; i < 32 * STR / 8; i += 256) d2[i] = s2[i];
    }
    __syncthreads();

    const int totW = gridDim.x * 4;
    const int numTiles = (E + 31) >> 5;
    int tile = blockIdx.x * 4 + wave;
    if (tile >= numTiles) return;

    // hoisted per-lane constants
    float bias1[8];
#pragma unroll
    for (int nt = 0; nt < 8; nt++) bias1[nt] = b1[nt * 16 + ln];
    const float g0 = gamma[ln], g1 = gamma[16 + ln];
    const float B0 = beta[ln],  B1 = beta[16 + ln];
    const float bb0 = b2[ln],   bb1 = b2[16 + ln];
    const bool evn = (ln & 1) == 0;
    const int fpair = evn ? ln : (15 + ln);

    u16* H = sH[wave];
    int p = 0;

    // load one tile's A-fragments into regs (+ idx to LDS, + edge_attr f32 pf)
    auto load_tile = [&](int t, bf16x8 (&af)[2][4], float4 (&pf)[2][2], int2* idxb) {
        long t32 = (long)t * 32;
#pragma unroll
        for (int m = 0; m < 2; m++) {
            long e  = t32 + m * 16 + ln;
            long ec = e < E ? e : (long)E - 1;
            int row = edge_index[ec];
            int col = edge_index[(long)E + ec];
            int gb  = batch[row];
            if (quad == 0) idxb[m * 16 + ln] = make_int2(row, col);
            af[m][0] = *reinterpret_cast<const bf16x8*>(nodeB + (long)col * 32 + quad * 8);
            af[m][1] = *reinterpret_cast<const bf16x8*>(nodeB + (long)row * 32 + quad * 8);
            af[m][3] = *reinterpret_cast<const bf16x8*>(globB + (long)gb * 32 + quad * 8);
            const float4* ea = reinterpret_cast<const float4*>(edge_attr + ec * 32 + quad * 8);
            pf[m][0] = ea[0];
            pf[m][1] = ea[1];
        }
    };

    // one pipeline step: compute tile `tile` from afC/pfC, prefetch next into afN/pfN
    auto step = [&](bf16x8 (&afC)[2][4], bf16x8 (&afN)[2][4],
                    float4 (&pfC)[2][2], float4 (&pfN)[2][2]) -> bool {
        // finish current tile's A: edge_attr seg f32 -> bf16
        afC[0][2] = cvt8(pfC[0][0], pfC[0][1]);
        afC[1][2] = cvt8(pfC[1][0], pfC[1][1]);

        const int tnext = tile + totW;
        const bool hn = tnext < numTiles;
        if (hn) load_tile(tnext, afN, pfN, sIdx[wave][p ^ 1]);
        __builtin_amdgcn_sched_barrier(0);   // pin prefetch issue before GEMM

        // ---- GEMM1: H = relu(Ein @ W1 + b1), weights from LDS ----
        f32x4 acc1[2][8];
#pragma unroll
        for (int mt = 0; mt < 2; mt++)
#pragma unroll
            for (int nt = 0; nt < 8; nt++) acc1[mt][nt] = (f32x4)0.f;

#pragma unroll
        for (int ks = 0; ks < 4; ks++) {
            const int ko = ks * 32 + quad * 8;
#pragma unroll
            for (int nt = 0; nt < 8; nt++) {
                bf16x8 bw = *reinterpret_cast<const bf16x8*>(sW1 + (nt * 16 + ln) * STR + ko);
                acc1[0][nt] = MFMA16(afC[0][ks], bw, acc1[0][nt], 0, 0, 0);
                acc1[1][nt] = MFMA16(afC[1][ks], bw, acc1[1][nt], 0, 0, 0);
            }
        }

        // ---- bias+relu, H -> LDS (A-operand layout) ----
#pragma unroll
        for (int nt = 0; nt < 8; nt++) {
#pragma unroll
            for (int mt = 0; mt < 2; mt++)
#pragma unroll
                for (int r = 0; r < 4; r++) {
                    float h = fmaxf(acc1[mt][nt][r] + bias1[nt], 0.f);
                    H[(mt * 16 + quad * 4 + r) * STR + nt * 16 + ln] = f2bf(h);
                }
        }

        // ---- GEMM2 ----
        f32x4 acc2[2][2];
#pragma unroll
        for (int mt = 0; mt < 2; mt++)
#pragma unroll
            for (int nt = 0; nt < 2; nt++) acc2[mt][nt] = (f32x4)0.f;

#pragma unroll
        for (int ks = 0; ks < 4; ks++) {
            const int ko = ks * 32 + quad * 8;
            bf16x8 a0 = *reinterpret_cast<const bf16x8*>(H + ln * STR + ko);
            bf16x8 a1 = *reinterpret_cast<const bf16x8*>(H + (16 + ln) * STR + ko);
#pragma unroll
            for (int nt = 0; nt < 2; nt++) {
                bf16x8 bw = *reinterpret_cast<const bf16x8*>(sW2 + (nt * 16 + ln) * STR + ko);
                acc2[0][nt] = MFMA16(a0, bw, acc2[0][nt], 0, 0, 0);
                acc2[1][nt] = MFMA16(a1, bw, acc2[1][nt], 0, 0, 0);
            }
        }

        // ---- epilogue: relu, LN, nt-store, pk-f16 atomics (fire-and-forget) ----
        int2* idxb = sIdx[wave][p];
        const long e0 = (long)tile * 32;
#pragma unroll
        for (int mt = 0; mt < 2; mt++) {
#pragma unroll
            for (int r = 0; r < 4; r++) {
                float v0 = fmaxf(acc2[mt][0][r] + bb0, 0.f);
                float v1 = fmaxf(acc2[mt][1][r] + bb1, 0.f);
                float s = v0 + v1, sq = v0 * v0 + v1 * v1;
#pragma unroll
                for (int m = 1; m < 16; m <<= 1) {
                    s  += __shfl_xor(s,  m, 64);
                    sq += __shfl_xor(sq, m, 64);
                }
                float mean = s * (1.f / 32.f);
                float var  = fmaxf(sq * (1.f / 32.f) - mean * mean, 0.f);
                float rs   = rsqrtf(var + LN_EPS);
                float y0 = (v0 - mean) * rs * g0 + B0;
                float y1 = (v1 - mean) * rs * g1 + B1;
                float p0 = __shfl_xor(y0, 1, 64);
                float p1 = __shfl_xor(y1, 1, 64);
                int rowl = mt * 16 + quad * 4 + r;
                long e = e0 + rowl;
                if (e < E) {
                    __builtin_nontemporal_store(y0, &edge_out[e * 32 + ln]);
                    __builtin_nontemporal_store(y1, &edge_out[e * 32 + 16 + ln]);
                    __half2 val = evn
                        ? __halves2half2(__float2half_rn(y0), __float2half_rn(p0))
                        : __halves2half2(__float2half_rn(p1), __float2half_rn(y1));
                    int2 rc = idxb[rowl];
                    unsafeAtomicAdd(reinterpret_cast<__half2*>(send_agg + (long)rc.x * 32 + fpair), val);
                    unsafeAtomicAdd(reinterpret_cast<__half2*>(recv_agg + (long)rc.y * 32 + fpair), val);
                }
            }
        }
        tile = tnext;
        p ^= 1;
        return hn;
    };

    bf16x8 af0[2][4], af1[2][4];
    float4 pf0[2][2], pf1[2][2];
    load_tile(tile, af0, pf0, sIdx[wave][0]);
    for (;;) {
        if (!step(af0, af1, pf0, pf1)) break;
        if (!step(af1, af0, pf1, pf0)) break;
    }
}

// ---------------------------------------------------------------------------
// Node model: 1 wave / 32 nodes. All inputs coalesced or cached; A-frags
// loaded directly into registers (bf16/f16 sources); weights from global
// (L1/L2-hot); H transpose via small LDS. n2g/e2g slot reduction as before.
// ---------------------------------------------------------------------------
__global__ __launch_bounds__(64, 2)
void node_mfma(const u16* __restrict__ nodeB, const u16* __restrict__ globB,
               const int* __restrict__ batch,
               const __half* __restrict__ send_agg,
               const __half* __restrict__ recv_agg,
               const u16* __restrict__ W1T, const float* __restrict__ b1,
               const u16* __restrict__ W2T, const float* __restrict__ b2,
               const float* __restrict__ gamma, const float* __restrict__ beta,
               float* __restrict__ node_out,
               float* __restrict__ n2g, float* __restrict__ e2g,
               int N)
{
    __shared__ __align__(16) u16 sH[32 * STR];
    __shared__ float sRed[8][64];       // [slot][n2g 0..31 | e2g 32..63]
    __shared__ int sSlotGb[8];
    __shared__ int sGb[32];

    const int lane = threadIdx.x;
    const int quad = lane >> 4;
    const int ln   = lane & 15;

    for (int i = lane; i < 512; i += 64) ((float*)sRed)[i] = 0.f;
    if (lane < 8) sSlotGb[lane] = -1;

    const long n0 = (long)blockIdx.x * 32;
    const int gbF = batch[n0 < N ? n0 : N - 1];

    // ---- A-fragments direct to registers ----
    bf16x8 af[2][4];
#pragma unroll
    for (int m = 0; m < 2; m++) {
        long n  = n0 + m * 16 + ln;
        long nc = n < N ? n : (long)N - 1;
        int gb  = batch[nc];
        if (quad == 0) sGb[m * 16 + ln] = gb;
        af[m][0] = *reinterpret_cast<const bf16x8*>(nodeB + nc * 32 + quad * 8);
        af[m][1] = *reinterpret_cast<const bf16x8*>(globB + (long)gb * 32 + quad * 8);
        uint4 rv = *reinterpret_cast<const uint4*>(recv_agg + nc * 32 + quad * 8);
        uint4 sv = *reinterpret_cast<const uint4*>(send_agg + nc * 32 + quad * 8);
        af[m][2] = cvtf16x8(rv);
        af[m][3] = cvtf16x8(sv);
    }

    // ---- GEMM1 ----
    f32x4 acc1[2][8];
#pragma unroll
    for (int mt = 0; mt < 2; mt++)
#pragma unroll
        for (int nt = 0; nt < 8; nt++) acc1[mt][nt] = (f32x4)0.f;

#pragma unroll
    for (int ks = 0; ks < 4; ks++) {
        const int ko = ks * 32 + quad * 8;
#pragma unroll
        for (int nt = 0; nt < 8; nt++) {
            bf16x8 bw = *reinterpret_cast<const bf16x8*>(W1T + (nt * 16 + ln) * STR + ko);
            acc1[0][nt] = MFMA16(af[0][ks], bw, acc1[0][nt], 0, 0, 0);
            acc1[1][nt] = MFMA16(af[1][ks], bw, acc1[1][nt], 0, 0, 0);
        }
    }

#pragma unroll
    for (int nt = 0; nt < 8; nt++) {
        float bias = b1[nt * 16 + ln];
#pragma unroll
        for (int mt = 0; mt < 2; mt++)
#pragma unroll
            for (int r = 0; r < 4; r++) {
                float h = fmaxf(acc1[mt][nt][r] + bias, 0.f);
                sH[(mt * 16 + quad * 4 + r) * STR + nt * 16 + ln] = f2bf(h);
            }
    }

    // ---- GEMM2 ----
    f32x4 acc2[2][2];
#pragma unroll
    for (int mt = 0; mt < 2; mt++)
#pragma unroll
        for (int nt = 0; nt < 2; nt++) acc2[mt][nt] = (f32x4)0.f;

#pragma unroll
    for (int ks = 0; ks < 4; ks++) {
        const int ko = ks * 32 + quad * 8;
        bf16x8 a0 = *reinterpret_cast<const bf16x8*>(sH + ln * STR + ko);
        bf16x8 a1 = *reinterpret_cast<const bf16x8*>(sH + (16 + ln) * STR + ko);
#pragma unroll
        for (int nt = 0; nt < 2; nt++) {
            bf16x8 bw = *reinterpret_cast<const bf16x8*>(W2T + (nt * 16 + ln) * STR + ko);
            acc2[0][nt] = MFMA16(a0, bw, acc2[0][nt], 0, 0, 0);
            acc2[1][nt] = MFMA16(a1, bw, acc2[1][nt], 0, 0, 0);
        }
    }

    const float g0 = gamma[ln], g1 = gamma[16 + ln];
    const float B0 = beta[ln],  B1 = beta[16 + ln];
    const float bb0 = b2[ln],   bb1 = b2[16 + ln];

#pragma unroll
    for (int mt = 0; mt < 2; mt++) {
#pragma unroll
        for (int r = 0; r < 4; r++) {
            float v0 = fmaxf(acc2[mt][0][r] + bb0, 0.f);
            float v1 = fmaxf(acc2[mt][1][r] + bb1, 0.f);
            float s = v0 + v1, sq = v0 * v0 + v1 * v1;
#pragma unroll
            for (int m = 1; m < 16; m <<= 1) {
                s  += __shfl_xor(s,  m, 64);
                sq += __shfl_xor(sq, m, 64);
            }
            float mean = s * (1.f / 32.f);
            float var  = fmaxf(sq * (1.f / 32.f) - mean * mean, 0.f);
            float rs   = rsqrtf(var + LN_EPS);
            float y0 = (v0 - mean) * rs * g0 + B0;
            float y1 = (v1 - mean) * rs * g1 + B1;
            int rowl = mt * 16 + quad * 4 + r;
            long n = n0 + rowl;
            if (n < N) {
                node_out[n * 32 + ln]      = y0;
                node_out[n * 32 + 16 + ln] = y1;
                int gb = sGb[rowl];
                float sa0 = __half2float(send_agg[n * 32 + ln]);
                float sa1 = __half2float(send_agg[n * 32 + 16 + ln]);
                int slot = gb - gbF;
                if (slot >= 0 && slot < 8) {
                    if (ln == 0) sSlotGb[slot] = gb;
                    atomicAdd(&sRed[slot][ln],      y0);
                    atomicAdd(&sRed[slot][16 + ln], y1);
                    atomicAdd(&sRed[slot][32 + ln], sa0);
                    atomicAdd(&sRed[slot][48 + ln], sa1);
                } else {
                    unsafeAtomicAdd(n2g + (long)gb * 32 + ln,      y0);
                    unsafeAtomicAdd(n2g + (long)gb * 32 + 16 + ln, y1);
                    unsafeAtomicAdd(e2g + (long)gb * 32 + ln,      sa0);
                    unsafeAtomicAdd(e2g + (long)gb * 32 + 16 + ln, sa1);
                }
            }
        }
    }

    // flush block partials (single wave: LDS ops are wave-ordered, no barrier)
#pragma unroll 1
    for (int s2 = 0; s2 < 8; s2++) {
        int gb2 = sSlotGb[s2];
        if (gb2 >= 0) {
            float v = sRed[s2][lane];
            float* dst = (lane < 32) ? (n2g + (long)gb2 * 32 + lane)
                                     : (e2g + (long)gb2 * 32 + (lane - 32));
            unsafeAtomicAdd(dst, v);
        }
    }
}

// ---------------------------------------------------------------------------
// Global model (tiny, fp32 exact)
// ---------------------------------------------------------------------------
__global__ void global_kernel(const float* __restrict__ n2g,
                              const float* __restrict__ e2g,
                              const float* __restrict__ global_attr,
                              const float* __restrict__ W1, const float* __restrict__ b1,
                              const float* __restrict__ W2, const float* __restrict__ b2,
                              float* __restrict__ out)
{
    __shared__ float gin[96];
    __shared__ float h[128];
    int g = blockIdx.x, t = threadIdx.x;
    if (t < 32) {
        gin[t]      = n2g[g * 32 + t];
        gin[32 + t] = e2g[g * 32 + t];
        gin[64 + t] = global_attr[g * 32 + t];
    }
    __syncthreads();
    float acc = b1[t];
#pragma unroll 1
    for (int k = 0; k < 96; k++) acc = fmaf(gin[k], W1[k * 128 + t], acc);
    h[t] = fmaxf(acc, 0.f);
    __syncthreads();
    if (t < 32) {
        float o = b2[t];
#pragma unroll 1
        for (int j = 0; j < 128; j++) o = fmaf(h[j], W2[j * 32 + t], o);
        out[g * 32 + t] = fmaxf(o, 0.f);
    }
}

// ---------------------------------------------------------------------------
extern "C" void kernel_launch(void* const* d_in, const int* in_sizes, int n_in,
                              void* d_out, int out_size, void* d_ws, size_t ws_size,
                              hipStream_t stream)
{
    const float* edge_attr   = (const float*)d_in[0];
    const float* node_attr   = (const float*)d_in[1];
    const float* global_attr = (const float*)d_in[2];
    const int*   edge_index  = (const int*)d_in[3];
    const int*   batch       = (const int*)d_in[4];
    const float* eW1 = (const float*)d_in[5];
    const float* eb1 = (const float*)d_in[6];
    const float* eW2 = (const float*)d_in[7];
    const float* eb2 = (const float*)d_in[8];
    const float* eg  = (const float*)d_in[9];
    const float* eB  = (const float*)d_in[10];
    const float* nW1 = (const float*)d_in[11];
    const float* nb1 = (const float*)d_in[12];
    const float* nW2 = (const float*)d_in[13];
    const float* nb2 = (const float*)d_in[14];
    const float* ng  = (const float*)d_in[15];
    const float* nB  = (const float*)d_in[16];
    const float* gW1 = (const float*)d_in[17];
    const float* gb1 = (const float*)d_in[18];
    const float* gW2 = (const float*)d_in[19];
    const float* gb2 = (const float*)d_in[20];

    const int E = in_sizes[0] / 32;
    const int N = in_sizes[1] / 32;
    const int G = in_sizes[2] / 32;

    float* out      = (float*)d_out;
    float* edge_out = out;
    float* node_out = out + (size_t)E * 32;
    float* glob_out = out + (size_t)(E + N) * 32;

    // ws: send f16 | recv f16 | n2g | e2g | nodeB bf16 | globB bf16 | weights
    __half* send_agg = (__half*)d_ws;
    __half* recv_agg = send_agg + (size_t)N * 32;
    float*  n2g      = (float*)(recv_agg + (size_t)N * 32);
    float*  e2g      = n2g + (size_t)G * 32;
    u16* nodeB = (u16*)(e2g + (size_t)G * 32);
    u16* globB = nodeB + (size_t)N * 32;
    u16* eW1T  = globB + (size_t)G * 32;
    u16* eW2T  = eW1T + 128 * STR;
    u16* nW1T  = eW2T + 32 * STR;
    u16* nW2T  = nW1T + 128 * STR;

    size_t zero_bytes = (size_t)N * 32 * 2 * sizeof(__half)
                      + (size_t)G * 32 * 2 * sizeof(float);
    hipMemsetAsync(d_ws, 0, zero_bytes, stream);

    prep_kernel<<<64, 256, 0, stream>>>(eW1, eW2, nW1, nW2, eW1T, eW2T, nW1T, nW2T);
    cvt_nodes<<<784, 256, 0, stream>>>(node_attr, global_attr, nodeB, globB, N * 4, G * 4);

    edge_mfma<<<512, 256, 0, stream>>>(
        edge_attr, edge_index, batch, nodeB, globB,
        eW1T, eb1, eW2T, eb2, eg, eB,
        edge_out, send_agg, recv_agg, E);

    node_mfma<<<(N + 31) / 32, 64, 0, stream>>>(
        nodeB, globB, batch, send_agg, recv_agg,
        nW1T, nb1, nW2T, nb2, ng, nB,
        node_out, n2g, e2g, N);

    global_kernel<<<G, 128, 0, stream>>>(
        n2g, e2g, global_attr, gW1, gb1, gW2, gb2, glob_out);
}

// Round 5
// 634.353 us; speedup vs baseline: 2.3235x; 1.0310x over previous
//
#include <hip/hip_runtime.h>
#include <hip/hip_fp16.h>
#include <cstdint>
#include <cstddef>

#define LN_EPS 1e-5f
#define STR 136   // padded row stride in bf16 elems (272B, 16B-mult)

typedef unsigned short u16;
typedef unsigned int   u32;
typedef __attribute__((ext_vector_type(8))) short bf16x8;
typedef __attribute__((ext_vector_type(4))) float f32x4;

#define MFMA16 __builtin_amdgcn_mfma_f32_16x16x32_bf16

__device__ __forceinline__ u16 f2bf(float f) {
    u32 x = __float_as_uint(f);
    return (u16)((x + 0x7fffu + ((x >> 16) & 1u)) >> 16);   // RNE, finite inputs
}
__device__ __forceinline__ u32 pack2(float x, float y) {
    return (u32)f2bf(x) | ((u32)f2bf(y) << 16);
}
__device__ __forceinline__ bf16x8 cvt8(float4 a, float4 b) {
    union { bf16x8 v; u32 w[4]; } u;
    u.w[0] = pack2(a.x, a.y); u.w[1] = pack2(a.z, a.w);
    u.w[2] = pack2(b.x, b.y); u.w[3] = pack2(b.z, b.w);
    return u.v;
}
__device__ __forceinline__ u32 h2_to_bf2(u32 h) {
    __half2 hv = *reinterpret_cast<__half2*>(&h);
    float lo = __half2float(__low2half(hv));
    float hi = __half2float(__high2half(hv));
    return pack2(lo, hi);
}
__device__ __forceinline__ bf16x8 cvtf16x8(uint4 a) {
    union { bf16x8 v; u32 w[4]; } u;
    u.w[0] = h2_to_bf2(a.x); u.w[1] = h2_to_bf2(a.y);
    u.w[2] = h2_to_bf2(a.z); u.w[3] = h2_to_bf2(a.w);
    return u.v;
}

// ---------------------------------------------------------------------------
// prep: W1 [128,128] -> W1T bf16 [n][k] stride STR; W2 [128,32] -> W2T
// ---------------------------------------------------------------------------
__global__ void prep_kernel(const float* __restrict__ eW1, const float* __restrict__ eW2,
                            const float* __restrict__ nW1, const float* __restrict__ nW2,
                            u16* eW1T, u16* eW2T, u16* nW1T, u16* nW2T)
{
    int idx = blockIdx.x * 256 + threadIdx.x;
    if (idx < 16384) {
        int k = idx >> 7, n = idx & 127;
        eW1T[n * STR + k] = f2bf(eW1[idx]);
        nW1T[n * STR + k] = f2bf(nW1[idx]);
    }
    if (idx < 4096) {
        int k = idx >> 5, n = idx & 31;
        eW2T[n * STR + k] = f2bf(eW2[idx]);
        nW2T[n * STR + k] = f2bf(nW2[idx]);
    }
}

// node_attr / global_attr f32 -> bf16 tables
__global__ void cvt_nodes(const float* __restrict__ node_attr,
                          const float* __restrict__ global_attr,
                          u16* __restrict__ nodeB, u16* __restrict__ globB,
                          int n8, int g8)
{
    int stride = gridDim.x * 256;
    for (int i = blockIdx.x * 256 + threadIdx.x; i < n8 + g8; i += stride) {
        const float4* s; uint4* d; int j;
        if (i < n8) { s = (const float4*)node_attr;   d = (uint4*)nodeB; j = i; }
        else        { s = (const float4*)global_attr; d = (uint4*)globB; j = i - n8; }
        float4 a = s[2 * j], b = s[2 * j + 1];
        uint4 o;
        o.x = pack2(a.x, a.y); o.y = pack2(a.z, a.w);
        o.z = pack2(b.x, b.y); o.w = pack2(b.z, b.w);
        d[j] = o;
    }
}

// per-edge graph id: collapses the edge gather chain from 3-deep to 2-deep
__global__ void gbe_kernel(const int* __restrict__ edge_index,
                           const int* __restrict__ batch,
                           int* __restrict__ gbE, int E)
{
    int stride = gridDim.x * 256;
    for (int e = blockIdx.x * 256 + threadIdx.x; e < E; e += stride)
        gbE[e] = batch[edge_index[e]];
}

// ---------------------------------------------------------------------------
// Edge model: persistent waves, 32 edges/tile, 3-stage software pipeline.
// R4 post-mortem: the 2-stage pipeline exposed ~1K cyc/step of dependent
// idx->batch->gather latency (the sched_barrier pinned the idx waits before
// the GEMM). Now: body t issues idx(t+2) [regs], gathers af(t+1) using
// idx(t+1) [arrived], computes tile t from af(t) [arrived]. Every s_waitcnt
// covers one full compute phase. W2 fragments are loop-invariant registers.
// ---------------------------------------------------------------------------
__global__ __launch_bounds__(256, 2)
void edge_mfma(const float* __restrict__ edge_attr,
               const int* __restrict__ edge_index,
               const int* __restrict__ gbE,
               const u16* __restrict__ nodeB,
               const u16* __restrict__ globB,
               const u16* __restrict__ W1T, const float* __restrict__ b1,
               const u16* __restrict__ W2T, const float* __restrict__ b2,
               const float* __restrict__ gamma, const float* __restrict__ beta,
               float* __restrict__ edge_out,
               __half* __restrict__ send_agg, __half* __restrict__ recv_agg,
               int E)
{
    __shared__ __align__(16) u16 sW1[128 * STR];
    __shared__ __align__(16) u16 sH[4][32 * STR];
    __shared__ int2 sIdx[4][2][32];

    const int tid  = threadIdx.x;
    const int wave = tid >> 6;
    const int lane = tid & 63;
    const int quad = lane >> 4;
    const int ln   = lane & 15;

    // ---- stage W1 to LDS (once per block) ----
    {
        const uint4* s1 = reinterpret_cast<const uint4*>(W1T);
        uint4* d1 = reinterpret_cast<uint4*>(sW1);
        for (int i = tid; i < 128 * STR / 8; i += 256) d1[i] = s1[i];
    }
    __syncthreads();

    const int totW = gridDim.x * 4;
    const int numTiles = (E + 31) >> 5;
    int tile = blockIdx.x * 4 + wave;
    if (tile >= numTiles) return;

    // hoisted per-lane constants
    float bias1[8];
#pragma unroll
    for (int nt = 0; nt < 8; nt++) bias1[nt] = b1[nt * 16 + ln];
    const float g0 = gamma[ln], g1 = gamma[16 + ln];
    const float B0 = beta[ln],  B1 = beta[16 + ln];
    const float bb0 = b2[ln],   bb1 = b2[16 + ln];
    const bool evn = (ln & 1) == 0;
    const int fpair = evn ? ln : (15 + ln);

    // W2 B-fragments: loop-invariant, live in registers (32 VGPR)
    bf16x8 w2f[2][4];
#pragma unroll
    for (int nt = 0; nt < 2; nt++)
#pragma unroll
        for (int ks = 0; ks < 4; ks++)
            w2f[nt][ks] = *reinterpret_cast<const bf16x8*>(
                W2T + (nt * 16 + ln) * STR + ks * 32 + quad * 8);

    u16* H = sH[wave];
    int p = 0;
    float4 pf[2][2];   // edge_attr f32 staging (single buffer)

    // stage A: independent idx loads for a tile (row, col, gb)
    auto load_idx = [&](int t, int (&row)[2], int (&col)[2], int (&gb)[2]) {
#pragma unroll
        for (int m = 0; m < 2; m++) {
            long e  = (long)t * 32 + m * 16 + ln;
            long ec = e < E ? e : (long)E - 1;
            row[m] = edge_index[ec];
            col[m] = edge_index[(long)E + ec];
            gb[m]  = gbE[ec];
        }
    };
    // stage B: gathers using already-arrived idx regs
    auto load_af = [&](int t, const int (&row)[2], const int (&col)[2], const int (&gb)[2],
                       bf16x8 (&af)[2][4], int2* idxb) {
        long t32 = (long)t * 32;
#pragma unroll
        for (int m = 0; m < 2; m++) {
            if (quad == 0) idxb[m * 16 + ln] = make_int2(row[m], col[m]);
            af[m][0] = *reinterpret_cast<const bf16x8*>(nodeB + (long)col[m] * 32 + quad * 8);
            af[m][1] = *reinterpret_cast<const bf16x8*>(nodeB + (long)row[m] * 32 + quad * 8);
            af[m][3] = *reinterpret_cast<const bf16x8*>(globB + (long)gb[m] * 32 + quad * 8);
            long e  = t32 + m * 16 + ln;
            long ec = e < E ? e : (long)E - 1;
            const float4* ea = reinterpret_cast<const float4*>(edge_attr + ec * 32 + quad * 8);
            pf[m][0] = ea[0];
            pf[m][1] = ea[1];
        }
    };

    // one pipeline step: compute `tile` from afC; prefetch idx(t+2)->idxF, af(t+1)->afN
    auto step = [&](bf16x8 (&afC)[2][4], bf16x8 (&afN)[2][4],
                    int (&rowF)[2], int (&colF)[2], int (&gbF)[2],
                    int (&rowN)[2], int (&colN)[2], int (&gbN)[2]) -> bool {
        // finish current tile's A (pf arrived one step ago); frees pf regs
        afC[0][2] = cvt8(pf[0][0], pf[0][1]);
        afC[1][2] = cvt8(pf[1][0], pf[1][1]);

        const int t2 = tile + 2 * totW;
        if (t2 < numTiles) load_idx(t2, rowF, colF, gbF);
        const int tn = tile + totW;
        const bool hn = tn < numTiles;
        if (hn) load_af(tn, rowN, colN, gbN, afN, sIdx[wave][p ^ 1]);
        __builtin_amdgcn_sched_barrier(0);   // pin prefetch issue before GEMM

        // ---- GEMM1: H = relu(Ein @ W1 + b1), weights from LDS ----
        f32x4 acc1[2][8];
#pragma unroll
        for (int mt = 0; mt < 2; mt++)
#pragma unroll
            for (int nt = 0; nt < 8; nt++) acc1[mt][nt] = (f32x4)0.f;

#pragma unroll
        for (int ks = 0; ks < 4; ks++) {
            const int ko = ks * 32 + quad * 8;
#pragma unroll
            for (int nt = 0; nt < 8; nt++) {
                bf16x8 bw = *reinterpret_cast<const bf16x8*>(sW1 + (nt * 16 + ln) * STR + ko);
                acc1[0][nt] = MFMA16(afC[0][ks], bw, acc1[0][nt], 0, 0, 0);
                acc1[1][nt] = MFMA16(afC[1][ks], bw, acc1[1][nt], 0, 0, 0);
            }
        }

        // ---- bias+relu, H -> LDS (A-operand layout) ----
#pragma unroll
        for (int nt = 0; nt < 8; nt++) {
#pragma unroll
            for (int mt = 0; mt < 2; mt++)
#pragma unroll
                for (int r = 0; r < 4; r++) {
                    float h = fmaxf(acc1[mt][nt][r] + bias1[nt], 0.f);
                    H[(mt * 16 + quad * 4 + r) * STR + nt * 16 + ln] = f2bf(h);
                }
        }

        // ---- GEMM2 (B from registers) ----
        f32x4 acc2[2][2];
#pragma unroll
        for (int mt = 0; mt < 2; mt++)
#pragma unroll
            for (int nt = 0; nt < 2; nt++) acc2[mt][nt] = (f32x4)0.f;

#pragma unroll
        for (int ks = 0; ks < 4; ks++) {
            const int ko = ks * 32 + quad * 8;
            bf16x8 a0 = *reinterpret_cast<const bf16x8*>(H + ln * STR + ko);
            bf16x8 a1 = *reinterpret_cast<const bf16x8*>(H + (16 + ln) * STR + ko);
#pragma unroll
            for (int nt = 0; nt < 2; nt++) {
                acc2[0][nt] = MFMA16(a0, w2f[nt][ks], acc2[0][nt], 0, 0, 0);
                acc2[1][nt] = MFMA16(a1, w2f[nt][ks], acc2[1][nt], 0, 0, 0);
            }
        }

        // ---- epilogue: relu, LN, nt-store, pk-f16 atomics (fire-and-forget) ----
        int2* idxb = sIdx[wave][p];
        const long e0 = (long)tile * 32;
#pragma unroll
        for (int mt = 0; mt < 2; mt++) {
#pragma unroll
            for (int r = 0; r < 4; r++) {
                float v0 = fmaxf(acc2[mt][0][r] + bb0, 0.f);
                float v1 = fmaxf(acc2[mt][1][r] + bb1, 0.f);
                float s = v0 + v1, sq = v0 * v0 + v1 * v1;
#pragma unroll
                for (int m = 1; m < 16; m <<= 1) {
                    s  += __shfl_xor(s,  m, 64);
                    sq += __shfl_xor(sq, m, 64);
                }
                float mean = s * (1.f / 32.f);
                float var  = fmaxf(sq * (1.f / 32.f) - mean * mean, 0.f);
                float rs   = rsqrtf(var + LN_EPS);
                float y0 = (v0 - mean) * rs * g0 + B0;
                float y1 = (v1 - mean) * rs * g1 + B1;
                float p0 = __shfl_xor(y0, 1, 64);
                float p1 = __shfl_xor(y1, 1, 64);
                int rowl = mt * 16 + quad * 4 + r;
                long e = e0 + rowl;
                if (e < E) {
                    __builtin_nontemporal_store(y0, &edge_out[e * 32 + ln]);
                    __builtin_nontemporal_store(y1, &edge_out[e * 32 + 16 + ln]);
                    __half2 val = evn
                        ? __halves2half2(__float2half_rn(y0), __float2half_rn(p0))
                        : __halves2half2(__float2half_rn(p1), __float2half_rn(y1));
                    int2 rc = idxb[rowl];
                    unsafeAtomicAdd(reinterpret_cast<__half2*>(send_agg + (long)rc.x * 32 + fpair), val);
                    unsafeAtomicAdd(reinterpret_cast<__half2*>(recv_agg + (long)rc.y * 32 + fpair), val);
                }
            }
        }
        tile = tn;
        p ^= 1;
        return hn;
    };

    // ---- prologue: idx(t0), idx(t1), af(t0) ----
    int rowA[2], colA[2], gbA[2], rowB[2], colB[2], gbB[2];
    bf16x8 afA[2][4], afB[2][4];
    load_idx(tile, rowA, colA, gbA);
    if (tile + totW < numTiles) load_idx(tile + totW, rowB, colB, gbB);
    load_af(tile, rowA, colA, gbA, afA, sIdx[wave][0]);

    for (;;) {
        if (!step(afA, afB, rowA, colA, gbA, rowB, colB, gbB)) break;
        if (!step(afB, afA, rowB, colB, gbB, rowA, colA, gbA)) break;
    }
}

// ---------------------------------------------------------------------------
// Node model: 1 wave / 32 nodes, register A-frags, global weights.
// ---------------------------------------------------------------------------
__global__ __launch_bounds__(64, 2)
void node_mfma(const u16* __restrict__ nodeB, const u16* __restrict__ globB,
               const int* __restrict__ batch,
               const __half* __restrict__ send_agg,
               const __half* __restrict__ recv_agg,
               const u16* __restrict__ W1T, const float* __restrict__ b1,
               const u16* __restrict__ W2T, const float* __restrict__ b2,
               const float* __restrict__ gamma, const float* __restrict__ beta,
               float* __restrict__ node_out,
               float* __restrict__ n2g, float* __restrict__ e2g,
               int N)
{
    __shared__ __align__(16) u16 sH[32 * STR];
    __shared__ float sRed[8][64];       // [slot][n2g 0..31 | e2g 32..63]
    __shared__ int sSlotGb[8];
    __shared__ int sGb[32];

    const int lane = threadIdx.x;
    const int quad = lane >> 4;
    const int ln   = lane & 15;

    for (int i = lane; i < 512; i += 64) ((float*)sRed)[i] = 0.f;
    if (lane < 8) sSlotGb[lane] = -1;

    const long n0 = (long)blockIdx.x * 32;
    const int gbF = batch[n0 < N ? n0 : N - 1];

    // ---- A-fragments direct to registers ----
    bf16x8 af[2][4];
#pragma unroll
    for (int m = 0; m < 2; m++) {
        long n  = n0 + m * 16 + ln;
        long nc = n < N ? n : (long)N - 1;
        int gb  = batch[nc];
        if (quad == 0) sGb[m * 16 + ln] = gb;
        af[m][0] = *reinterpret_cast<const bf16x8*>(nodeB + nc * 32 + quad * 8);
        af[m][1] = *reinterpret_cast<const bf16x8*>(globB + (long)gb * 32 + quad * 8);
        uint4 rv = *reinterpret_cast<const uint4*>(recv_agg + nc * 32 + quad * 8);
        uint4 sv = *reinterpret_cast<const uint4*>(send_agg + nc * 32 + quad * 8);
        af[m][2] = cvtf16x8(rv);
        af[m][3] = cvtf16x8(sv);
    }

    // ---- GEMM1 ----
    f32x4 acc1[2][8];
#pragma unroll
    for (int mt = 0; mt < 2; mt++)
#pragma unroll
        for (int nt = 0; nt < 8; nt++) acc1[mt][nt] = (f32x4)0.f;

#pragma unroll
    for (int ks = 0; ks < 4; ks++) {
        const int ko = ks * 32 + quad * 8;
#pragma unroll
        for (int nt = 0; nt < 8; nt++) {
            bf16x8 bw = *reinterpret_cast<const bf16x8*>(W1T + (nt * 16 + ln) * STR + ko);
            acc1[0][nt] = MFMA16(af[0][ks], bw, acc1[0][nt], 0, 0, 0);
            acc1[1][nt] = MFMA16(af[1][ks], bw, acc1[1][nt], 0, 0, 0);
        }
    }

#pragma unroll
    for (int nt = 0; nt < 8; nt++) {
        float bias = b1[nt * 16 + ln];
#pragma unroll
        for (int mt = 0; mt < 2; mt++)
#pragma unroll
            for (int r = 0; r < 4; r++) {
                float h = fmaxf(acc1[mt][nt][r] + bias, 0.f);
                sH[(mt * 16 + quad * 4 + r) * STR + nt * 16 + ln] = f2bf(h);
            }
    }

    // ---- GEMM2 ----
    f32x4 acc2[2][2];
#pragma unroll
    for (int mt = 0; mt < 2; mt++)
#pragma unroll
        for (int nt = 0; nt < 2; nt++) acc2[mt][nt] = (f32x4)0.f;

#pragma unroll
    for (int ks = 0; ks < 4; ks++) {
        const int ko = ks * 32 + quad * 8;
        bf16x8 a0 = *reinterpret_cast<const bf16x8*>(sH + ln * STR + ko);
        bf16x8 a1 = *reinterpret_cast<const bf16x8*>(sH + (16 + ln) * STR + ko);
#pragma unroll
        for (int nt = 0; nt < 2; nt++) {
            bf16x8 bw = *reinterpret_cast<const bf16x8*>(W2T + (nt * 16 + ln) * STR + ko);
            acc2[0][nt] = MFMA16(a0, bw, acc2[0][nt], 0, 0, 0);
            acc2[1][nt] = MFMA16(a1, bw, acc2[1][nt], 0, 0, 0);
        }
    }

    const float g0 = gamma[ln], g1 = gamma[16 + ln];
    const float B0 = beta[ln],  B1 = beta[16 + ln];
    const float bb0 = b2[ln],   bb1 = b2[16 + ln];

#pragma unroll
    for (int mt = 0; mt < 2; mt++) {
#pragma unroll
        for (int r = 0; r < 4; r++) {
            float v0 = fmaxf(acc2[mt][0][r] + bb0, 0.f);
            float v1 = fmaxf(acc2[mt][1][r] + bb1, 0.f);
            float s = v0 + v1, sq = v0 * v0 + v1 * v1;
#pragma unroll
            for (int m = 1; m < 16; m <<= 1) {
                s  += __shfl_xor(s,  m, 64);
                sq += __shfl_xor(sq, m, 64);
            }
            float mean = s * (1.f / 32.f);
            float var  = fmaxf(sq * (1.f / 32.f) - mean * mean, 0.f);
            float rs   = rsqrtf(var + LN_EPS);
            float y0 = (v0 - mean) * rs * g0 + B0;
            float y1 = (v1 - mean) * rs * g1 + B1;
            int rowl = mt * 16 + quad * 4 + r;
            long n = n0 + rowl;
            if (n < N) {
                node_out[n * 32 + ln]      = y0;
                node_out[n * 32 + 16 + ln] = y1;
                int gb = sGb[rowl];
                float sa0 = __half2float(send_agg[n * 32 + ln]);
                float sa1 = __half2float(send_agg[n * 32 + 16 + ln]);
                int slot = gb - gbF;
                if (slot >= 0 && slot < 8) {
                    if (ln == 0) sSlotGb[slot] = gb;
                    atomicAdd(&sRed[slot][ln],      y0);
                    atomicAdd(&sRed[slot][16 + ln], y1);
                    atomicAdd(&sRed[slot][32 + ln], sa0);
                    atomicAdd(&sRed[slot][48 + ln], sa1);
                } else {
                    unsafeAtomicAdd(n2g + (long)gb * 32 + ln,      y0);
                    unsafeAtomicAdd(n2g + (long)gb * 32 + 16 + ln, y1);
                    unsafeAtomicAdd(e2g + (long)gb * 32 + ln,      sa0);
                    unsafeAtomicAdd(e2g + (long)gb * 32 + 16 + ln, sa1);
                }
            }
        }
    }

    // flush block partials (single wave: LDS ops are wave-ordered)
#pragma unroll 1
    for (int s2 = 0; s2 < 8; s2++) {
        int gb2 = sSlotGb[s2];
        if (gb2 >= 0) {
            float v = sRed[s2][lane];
            float* dst = (lane < 32) ? (n2g + (long)gb2 * 32 + lane)
                                     : (e2g + (long)gb2 * 32 + (lane - 32));
            unsafeAtomicAdd(dst, v);
        }
    }
}

// ---------------------------------------------------------------------------
// Global model (tiny, fp32 exact)
// ---------------------------------------------------------------------------
__global__ void global_kernel(const float* __restrict__ n2g,
                              const float* __restrict__ e2g,
                              const float* __restrict__ global_attr,
                              const float* __restrict__ W1, const float* __restrict__ b1,
                              const float* __restrict__ W2, const float* __restrict__ b2,
                              float* __restrict__ out)
{
    __shared__ float gin[96];
    __shared__ float h[128];
    int g = blockIdx.x, t = threadIdx.x;
    if (t < 32) {
        gin[t]      = n2g[g * 32 + t];
        gin[32 + t] = e2g[g * 32 + t];
        gin[64 + t] = global_attr[g * 32 + t];
    }
    __syncthreads();
    float acc = b1[t];
#pragma unroll 1
    for (int k = 0; k < 96; k++) acc = fmaf(gin[k], W1[k * 128 + t], acc);
    h[t] = fmaxf(acc, 0.f);
    __syncthreads();
    if (t < 32) {
        float o = b2[t];
#pragma unroll 1
        for (int j = 0; j < 128; j++) o = fmaf(h[j], W2[j * 32 + t], o);
        out[g * 32 + t] = fmaxf(o, 0.f);
    }
}

// ---------------------------------------------------------------------------
extern "C" void kernel_launch(void* const* d_in, const int* in_sizes, int n_in,
                              void* d_out, int out_size, void* d_ws, size_t ws_size,
                              hipStream_t stream)
{
    const float* edge_attr   = (const float*)d_in[0];
    const float* node_attr   = (const float*)d_in[1];
    const float* global_attr = (const float*)d_in[2];
    const int*   edge_index  = (const int*)d_in[3];
    const int*   batch       = (const int*)d_in[4];
    const float* eW1 = (const float*)d_in[5];
    const float* eb1 = (const float*)d_in[6];
    const float* eW2 = (const float*)d_in[7];
    const float* eb2 = (const float*)d_in[8];
    const float* eg  = (const float*)d_in[9];
    const float* eB  = (const float*)d_in[10];
    const float* nW1 = (const float*)d_in[11];
    const float* nb1 = (const float*)d_in[12];
    const float* nW2 = (const float*)d_in[13];
    const float* nb2 = (const float*)d_in[14];
    const float* ng  = (const float*)d_in[15];
    const float* nB  = (const float*)d_in[16];
    const float* gW1 = (const float*)d_in[17];
    const float* gb1 = (const float*)d_in[18];
    const float* gW2 = (const float*)d_in[19];
    const float* gb2 = (const float*)d_in[20];

    const int E = in_sizes[0] / 32;
    const int N = in_sizes[1] / 32;
    const int G = in_sizes[2] / 32;

    float* out      = (float*)d_out;
    float* edge_out = out;
    float* node_out = out + (size_t)E * 32;
    float* glob_out = out + (size_t)(E + N) * 32;

    // ws: send f16 | recv f16 | n2g | e2g | nodeB bf16 | globB bf16 | gbE int | weights
    __half* send_agg = (__half*)d_ws;
    __half* recv_agg = send_agg + (size_t)N * 32;
    float*  n2g      = (float*)(recv_agg + (size_t)N * 32);
    float*  e2g      = n2g + (size_t)G * 32;
    u16* nodeB = (u16*)(e2g + (size_t)G * 32);
    u16* globB = nodeB + (size_t)N * 32;
    int* gbE   = (int*)(globB + (size_t)G * 32);
    u16* eW1T  = (u16*)(gbE + (size_t)E);
    u16* eW2T  = eW1T + 128 * STR;
    u16* nW1T  = eW2T + 32 * STR;
    u16* nW2T  = nW1T + 128 * STR;

    size_t zero_bytes = (size_t)N * 32 * 2 * sizeof(__half)
                      + (size_t)G * 32 * 2 * sizeof(float);
    hipMemsetAsync(d_ws, 0, zero_bytes, stream);

    prep_kernel<<<64, 256, 0, stream>>>(eW1, eW2, nW1, nW2, eW1T, eW2T, nW1T, nW2T);
    cvt_nodes<<<784, 256, 0, stream>>>(node_attr, global_attr, nodeB, globB, N * 4, G * 4);
    gbe_kernel<<<2048, 256, 0, stream>>>(edge_index, batch, gbE, E);

    edge_mfma<<<512, 256, 0, stream>>>(
        edge_attr, edge_index, gbE, nodeB, globB,
        eW1T, eb1, eW2T, eb2, eg, eB,
        edge_out, send_agg, recv_agg, E);

    node_mfma<<<(N + 31) / 32, 64, 0, stream>>>(
        nodeB, globB, batch, send_agg, recv_agg,
        nW1T, nb1, nW2T, nb2, ng, nB,
        node_out, n2g, e2g, N);

    global_kernel<<<G, 128, 0, stream>>>(
        n2g, e2g, global_attr, gW1, gb1, gW2, gb2, glob_out);
}